// Round 1
// baseline (34350.012 us; speedup 1.0000x reference)
//
#include <hip/hip_runtime.h>

#define TT 512
#define BB 64
#define II 512
#define HH 1024
#define NBLK 256
#define NTHR 512

typedef short bf16x8 __attribute__((ext_vector_type(8)));
typedef float f32x4 __attribute__((ext_vector_type(4)));

struct Params {
  const unsigned short* xb;   // [TT][BB][II] bf16
  unsigned short* h0;         // [2][BB][HH] bf16
  unsigned short* h1;         // [2][BB][HH] bf16
  unsigned int* bar;          // barrier: [0]=count, [1]=generation
  const float* wih0; const float* whh0; const float* bih0; const float* bhh0;
  const float* wih1; const float* whh1; const float* bih1; const float* bhh1;
  float* out;
};

__device__ __forceinline__ unsigned short f2bf(float f) {
  unsigned int u = __float_as_uint(f);
  u += 0x7fffu + ((u >> 16) & 1u);   // round-to-nearest-even
  return (unsigned short)(u >> 16);
}

__global__ void cvt_kernel(const float* __restrict__ x, unsigned short* __restrict__ xb, int n8) {
  int i = blockIdx.x * blockDim.x + threadIdx.x;
  int stride = gridDim.x * blockDim.x;
  for (; i < n8; i += stride) {
    const float4* p = (const float4*)(x) + (size_t)i * 2;
    float4 a = p[0], b = p[1];
    bf16x8 v;
    v[0] = (short)f2bf(a.x); v[1] = (short)f2bf(a.y); v[2] = (short)f2bf(a.z); v[3] = (short)f2bf(a.w);
    v[4] = (short)f2bf(b.x); v[5] = (short)f2bf(b.y); v[6] = (short)f2bf(b.z); v[7] = (short)f2bf(b.w);
    ((bf16x8*)xb)[i] = v;
  }
}

// sense-reversing grid barrier (all 256 blocks co-resident via cooperative launch)
__device__ __forceinline__ void gridbar(unsigned int* bar) {
  __threadfence();            // release all this thread's global writes (agent scope)
  __syncthreads();
  if (threadIdx.x == 0) {
    unsigned int gen = __hip_atomic_load(&bar[1], __ATOMIC_RELAXED, __HIP_MEMORY_SCOPE_AGENT);
    unsigned int arr = __hip_atomic_fetch_add(&bar[0], 1u, __ATOMIC_ACQ_REL, __HIP_MEMORY_SCOPE_AGENT);
    if (arr == NBLK - 1u) {
      __hip_atomic_store(&bar[0], 0u, __ATOMIC_RELAXED, __HIP_MEMORY_SCOPE_AGENT);
      __hip_atomic_store(&bar[1], gen + 1u, __ATOMIC_RELEASE, __HIP_MEMORY_SCOPE_AGENT);
    } else {
      while (__hip_atomic_load(&bar[1], __ATOMIC_ACQUIRE, __HIP_MEMORY_SCOPE_AGENT) == gen) {
        __builtin_amdgcn_s_sleep(2);
      }
    }
  }
  __syncthreads();
}

template <int LAYER>
__device__ void body(const Params& P, float (*pbuf)[64][36], float (*cb)[16]) {
  constexpr int K   = (LAYER == 0) ? (II + HH) : (2 * HH);   // 1536 / 2048
  constexpr int KSL = K / (8 * 32);                          // k-steps per wave: 6 / 8
  constexpr int KIH = (LAYER == 0) ? II : HH;                // boundary ih|hh

  const int tid  = threadIdx.x;
  const int lane = tid & 63;
  const int kh   = tid >> 6;          // wave id = k-eighth
  const int lbid = blockIdx.x & 127;
  const int mh   = lbid >> 6;         // batch half (32 rows)
  const int ns   = lbid & 63;         // 16 hidden units: [ns*16, ns*16+16)
  const int l15  = lane & 15;
  const int lk8  = (lane >> 4) * 8;

  const float* wih = (LAYER == 0) ? P.wih0 : P.wih1;
  const float* whh = (LAYER == 0) ? P.whh0 : P.whh1;

  // ---- load weight B-fragments into registers (held across the whole kernel) ----
  bf16x8 wf[4][KSL];
  #pragma unroll
  for (int nt = 0; nt < 4; ++nt) {          // nt == gate index (i,f,g,o)
    const int row = nt * HH + ns * 16 + l15;
    #pragma unroll
    for (int ks = 0; ks < KSL; ++ks) {
      int k = kh * (KSL * 32) + ks * 32 + lk8;
      const float* src = (k < KIH) ? (wih + (size_t)row * KIH + k)
                                   : (whh + (size_t)row * HH + (k - KIH));
      const float4* p4 = (const float4*)src;
      float4 a = p4[0], b = p4[1];
      bf16x8 v;
      v[0] = (short)f2bf(a.x); v[1] = (short)f2bf(a.y); v[2] = (short)f2bf(a.z); v[3] = (short)f2bf(a.w);
      v[4] = (short)f2bf(b.x); v[5] = (short)f2bf(b.y); v[6] = (short)f2bf(b.z); v[7] = (short)f2bf(b.w);
      wf[nt][ks] = v;
    }
  }

  // ---- per-thread bias (used by update threads tid<128) ----
  float bv[4];
  {
    const float* bi = (LAYER == 0) ? P.bih0 : P.bih1;
    const float* bh = (LAYER == 0) ? P.bhh0 : P.bhh1;
    int unit = ns * 16 + (tid & 15);
    #pragma unroll
    for (int g = 0; g < 4; ++g) bv[g] = bi[g * HH + unit] + bh[g * HH + unit];
  }

  // zero cell state
  if (tid < 128) {
    int q = tid >> 4, j = tid & 15;
    #pragma unroll
    for (int r = 0; r < 4; ++r) cb[q * 4 + r][j] = 0.f;
  }

  const size_t BH = (size_t)BB * HH;
  const size_t TBH = (size_t)TT * BH;

  #pragma unroll 1
  for (int p = 0; p <= TT; ++p) {
    const int t = (LAYER == 0) ? p : p - 1;
    const bool active = (LAYER == 0) ? (p < TT) : (p >= 1);

    f32x4 acc[2][4];
    if (active) {
      #pragma unroll
      for (int mt = 0; mt < 2; ++mt)
        #pragma unroll
        for (int nt = 0; nt < 4; ++nt) acc[mt][nt] = f32x4{0.f, 0.f, 0.f, 0.f};

      const unsigned short* h0prev = P.h0 + (size_t)((t + 1) & 1) * BH;
      const unsigned short* h0cur  = P.h0 + (size_t)(t & 1) * BH;
      const unsigned short* h1prev = P.h1 + (size_t)((t + 1) & 1) * BH;

      #pragma unroll
      for (int ks = 0; ks < KSL; ++ks) {
        int k = kh * (KSL * 32) + ks * 32 + lk8;
        #pragma unroll
        for (int mt = 0; mt < 2; ++mt) {
          int m = mh * 32 + mt * 16 + l15;
          const unsigned short* src;
          if (LAYER == 0) {
            src = (k < II) ? (P.xb + ((size_t)t * BB + m) * II + k)
                           : (h0prev + (size_t)m * HH + (k - II));
          } else {
            src = (k < HH) ? (h0cur + (size_t)m * HH + k)
                           : (h1prev + (size_t)m * HH + (k - HH));
          }
          bf16x8 av = *(const bf16x8*)src;
          #pragma unroll
          for (int nt = 0; nt < 4; ++nt)
            acc[mt][nt] = __builtin_amdgcn_mfma_f32_16x16x32_bf16(av, wf[nt][ks], acc[mt][nt], 0, 0, 0);
        }
      }
      // stage A: waves 4..7 write partials
      if (kh >= 4) {
        #pragma unroll
        for (int mt = 0; mt < 2; ++mt)
          #pragma unroll
          for (int nt = 0; nt < 4; ++nt) {
            int col = nt * 16 + l15;
            int mb  = mt * 16 + (lane >> 4) * 4;
            *(f32x4*)&pbuf[kh - 4][col][mb] = acc[mt][nt];
          }
      }
    }
    __syncthreads();
    // stage B: waves 0..3 fold in partner partials
    if (active && kh < 4) {
      #pragma unroll
      for (int mt = 0; mt < 2; ++mt)
        #pragma unroll
        for (int nt = 0; nt < 4; ++nt) {
          int col = nt * 16 + l15;
          int mb  = mt * 16 + (lane >> 4) * 4;
          f32x4 v = *(const f32x4*)&pbuf[kh][col][mb];
          acc[mt][nt] += v;
          *(f32x4*)&pbuf[kh][col][mb] = acc[mt][nt];
        }
    }
    __syncthreads();
    // cell update: 128 threads, each owns (m-quad q, unit j)
    if (active && tid < 128) {
      int q = tid >> 4, j = tid & 15;
      f32x4 gv[4];
      #pragma unroll
      for (int g = 0; g < 4; ++g) {
        int col = g * 16 + j;
        f32x4 s = *(const f32x4*)&pbuf[0][col][q * 4];
        #pragma unroll
        for (int w = 1; w < 4; ++w) s += *(const f32x4*)&pbuf[w][col][q * 4];
        gv[g] = s;
      }
      #pragma unroll
      for (int r = 0; r < 4; ++r) {
        int m = q * 4 + r;
        float iv = 1.f / (1.f + __expf(-(gv[0][r] + bv[0])));
        float fv = 1.f / (1.f + __expf(-(gv[1][r] + bv[1])));
        float gg = tanhf(gv[2][r] + bv[2]);
        float ov = 1.f / (1.f + __expf(-(gv[3][r] + bv[3])));
        float c = fv * cb[m][j] + iv * gg;
        cb[m][j] = c;
        float h = ov * tanhf(c);
        int mg = mh * 32 + m;
        int unit = ns * 16 + j;
        unsigned short hb = f2bf(h);
        if (LAYER == 0) {
          P.h0[(size_t)(t & 1) * BH + (size_t)mg * HH + unit] = hb;
          if (t == TT - 1) P.out[TBH + (size_t)mg * HH + unit] = h;
        } else {
          P.h1[(size_t)(t & 1) * BH + (size_t)mg * HH + unit] = hb;
          P.out[(size_t)t * BH + (size_t)mg * HH + unit] = h;
          if (t == TT - 1) P.out[TBH + BH + (size_t)mg * HH + unit] = h;
        }
      }
    }
    gridbar(P.bar);
  }

  // final cell state c_f
  if (tid < 128) {
    int q = tid >> 4, j = tid & 15;
    #pragma unroll
    for (int r = 0; r < 4; ++r) {
      int m = q * 4 + r;
      int mg = mh * 32 + m;
      int unit = ns * 16 + j;
      P.out[TBH + (size_t)(2 + LAYER) * BH + (size_t)mg * HH + unit] = cb[m][j];
    }
  }
}

__global__ void __launch_bounds__(NTHR, 2) lstm_kernel(Params P) {
  __shared__ float pbuf[4][64][36];   // [wave-pair][gate-col][m padded]
  __shared__ float cb[32][16];        // cell state: [m-local][unit-local]
  if (blockIdx.x < 128) body<0>(P, pbuf, cb);
  else                  body<1>(P, pbuf, cb);
}

extern "C" void kernel_launch(void* const* d_in, const int* in_sizes, int n_in,
                              void* d_out, int out_size, void* d_ws, size_t ws_size,
                              hipStream_t stream) {
  const float* x    = (const float*)d_in[0];
  Params P;
  P.wih0 = (const float*)d_in[1];
  P.whh0 = (const float*)d_in[2];
  P.bih0 = (const float*)d_in[3];
  P.bhh0 = (const float*)d_in[4];
  P.wih1 = (const float*)d_in[5];
  P.whh1 = (const float*)d_in[6];
  P.bih1 = (const float*)d_in[7];
  P.bhh1 = (const float*)d_in[8];
  P.out  = (float*)d_out;

  char* ws = (char*)d_ws;
  P.bar = (unsigned int*)ws;
  P.xb  = (const unsigned short*)(ws + 256);
  unsigned short* xb_w = (unsigned short*)(ws + 256);
  P.h0  = (unsigned short*)(ws + 256 + (size_t)TT * BB * II * 2);
  P.h1  = P.h0 + (size_t)2 * BB * HH;

  // re-init mutable state every launch (ws is poisoned before timing)
  hipMemsetAsync((void*)P.bar, 0, 256, stream);
  hipMemsetAsync((void*)P.h0, 0, (size_t)4 * BB * HH * sizeof(unsigned short), stream);

  int n8 = TT * BB * II / 8;
  cvt_kernel<<<2048, 256, 0, stream>>>(x, xb_w, n8);

  void* args[] = { &P };
  hipLaunchCooperativeKernel((void*)lstm_kernel, dim3(NBLK), dim3(NTHR), args, 0, stream);
}

// Round 2
// 4356.104 us; speedup vs baseline: 7.8855x; 7.8855x over previous
//
#include <hip/hip_runtime.h>

#define TT 512
#define BB 64
#define II 512
#define HH 1024
#define NBLK 256
#define NTHR 512
#define NCTR 32
#define CSTRIDE 32   // u32 stride between counters = 128B

typedef short bf16x8 __attribute__((ext_vector_type(8)));
typedef float f32x4 __attribute__((ext_vector_type(4)));
typedef int   i32x4 __attribute__((ext_vector_type(4)));

struct Params {
  const unsigned short* xb;   // [TT][BB][II] bf16
  unsigned short* h0;         // [2][BB][HH] bf16
  unsigned short* h1;         // [2][BB][HH] bf16
  unsigned int* ctr;          // 32 arrival counters, 128B apart
  const float* wih0; const float* whh0; const float* bih0; const float* bhh0;
  const float* wih1; const float* whh1; const float* bih1; const float* bhh1;
  float* out;
};

__device__ __forceinline__ unsigned short f2bf(float f) {
  unsigned int u = __float_as_uint(f);
  u += 0x7fffu + ((u >> 16) & 1u);   // round-to-nearest-even
  return (unsigned short)(u >> 16);
}

// coherence-point (bypass L1+L2) 16B load — cross-XCD coherent without fences
__device__ __forceinline__ bf16x8 ld_bypass(const unsigned short* p) {
  i32x4 r;
  asm volatile("global_load_dwordx4 %0, %1, off sc0 sc1" : "=v"(r) : "v"(p));
  return __builtin_bit_cast(bf16x8, r);
}

// coherence-point 2B store (write-through)
__device__ __forceinline__ void st_bypass_u16(unsigned short* p, unsigned int v) {
  asm volatile("global_store_short %0, %1, off sc0 sc1" :: "v"(p), "v"(v) : "memory");
}

__global__ void cvt_kernel(const float* __restrict__ x, unsigned short* __restrict__ xb, int n8) {
  int i = blockIdx.x * blockDim.x + threadIdx.x;
  int stride = gridDim.x * blockDim.x;
  for (; i < n8; i += stride) {
    const float4* p = (const float4*)(x) + (size_t)i * 2;
    float4 a = p[0], b = p[1];
    bf16x8 v;
    v[0] = (short)f2bf(a.x); v[1] = (short)f2bf(a.y); v[2] = (short)f2bf(a.z); v[3] = (short)f2bf(a.w);
    v[4] = (short)f2bf(b.x); v[5] = (short)f2bf(b.y); v[6] = (short)f2bf(b.z); v[7] = (short)f2bf(b.w);
    ((bf16x8*)xb)[i] = v;
  }
}

// Fence-free hierarchical grid barrier:
//  - producers publish data with sc0sc1 stores + vmcnt(0) BEFORE calling this
//  - arrival: 1 relaxed atomic add per block, spread over 32 cachelines (8 adds each)
//  - departure: wave-0 lanes 0..31 of EVERY block poll the 32 counters (relaxed,
//    device-scope => bypass load). No leader, no generation broadcast, no cache fences.
__device__ __forceinline__ void gridbar(unsigned int* ctr, unsigned int target, int tid) {
  asm volatile("s_waitcnt vmcnt(0)" ::: "memory");   // drain sc0sc1 data stores
  __syncthreads();                                   // all waves in block done
  if (tid == 0)
    __hip_atomic_fetch_add(&ctr[(blockIdx.x & (NCTR - 1)) * CSTRIDE], 1u,
                           __ATOMIC_RELAXED, __HIP_MEMORY_SCOPE_AGENT);
  if (tid < NCTR) {
    while (__hip_atomic_load(&ctr[tid * CSTRIDE], __ATOMIC_RELAXED,
                             __HIP_MEMORY_SCOPE_AGENT) < target) {
      __builtin_amdgcn_s_sleep(1);
    }
  }
  __syncthreads();
}

template <int LAYER>
__device__ void body(const Params& P, float (*pbuf)[64][36], float (*cb)[16]) {
  constexpr int K   = (LAYER == 0) ? (II + HH) : (2 * HH);   // 1536 / 2048
  constexpr int KSL = K / (8 * 32);                          // k-steps per wave: 6 / 8
  constexpr int KB  = KSL / 2;                               // load batch: 3 / 4
  constexpr int KIH = (LAYER == 0) ? II : HH;

  const int tid  = threadIdx.x;
  const int lane = tid & 63;
  const int kh   = tid >> 6;          // wave id = k-eighth
  const int lbid = blockIdx.x & 127;
  const int mh   = lbid >> 6;         // batch half (32 rows)
  const int ns   = lbid & 63;         // 16 hidden units: [ns*16, ns*16+16)
  const int l15  = lane & 15;
  const int lk8  = (lane >> 4) * 8;

  const float* wih = (LAYER == 0) ? P.wih0 : P.wih1;
  const float* whh = (LAYER == 0) ? P.whh0 : P.whh1;

  // ---- weight B-fragments in registers for the whole kernel ----
  bf16x8 wf[4][KSL];
  #pragma unroll
  for (int nt = 0; nt < 4; ++nt) {          // gate index (i,f,g,o)
    const int row = nt * HH + ns * 16 + l15;
    #pragma unroll
    for (int ks = 0; ks < KSL; ++ks) {
      int k = kh * (KSL * 32) + ks * 32 + lk8;
      const float* src = (k < KIH) ? (wih + (size_t)row * KIH + k)
                                   : (whh + (size_t)row * HH + (k - KIH));
      const float4* p4 = (const float4*)src;
      float4 a = p4[0], b = p4[1];
      bf16x8 v;
      v[0] = (short)f2bf(a.x); v[1] = (short)f2bf(a.y); v[2] = (short)f2bf(a.z); v[3] = (short)f2bf(a.w);
      v[4] = (short)f2bf(b.x); v[5] = (short)f2bf(b.y); v[6] = (short)f2bf(b.z); v[7] = (short)f2bf(b.w);
      wf[nt][ks] = v;
    }
  }

  // ---- per-thread bias (update threads tid<128) ----
  float bv[4];
  {
    const float* bi = (LAYER == 0) ? P.bih0 : P.bih1;
    const float* bh = (LAYER == 0) ? P.bhh0 : P.bhh1;
    int unit = ns * 16 + (tid & 15);
    #pragma unroll
    for (int g = 0; g < 4; ++g) bv[g] = bi[g * HH + unit] + bh[g * HH + unit];
  }

  if (tid < 128) {
    int q = tid >> 4, j = tid & 15;
    #pragma unroll
    for (int r = 0; r < 4; ++r) cb[q * 4 + r][j] = 0.f;
  }

  const size_t BH  = (size_t)BB * HH;
  const size_t TBH = (size_t)TT * BH;

  #pragma unroll 1
  for (int p = 0; p <= TT; ++p) {
    const int t = (LAYER == 0) ? p : p - 1;
    const bool active = (LAYER == 0) ? (p < TT) : (p >= 1);

    f32x4 acc[2][4];
    if (active) {
      #pragma unroll
      for (int mt = 0; mt < 2; ++mt)
        #pragma unroll
        for (int nt = 0; nt < 4; ++nt) acc[mt][nt] = f32x4{0.f, 0.f, 0.f, 0.f};

      const unsigned short* h0prev = P.h0 + (size_t)((t + 1) & 1) * BH;
      const unsigned short* h0cur  = P.h0 + (size_t)(t & 1) * BH;
      const unsigned short* h1prev = P.h1 + (size_t)((t + 1) & 1) * BH;

      #pragma unroll
      for (int half = 0; half < 2; ++half) {
        bf16x8 af[KB][2];
        #pragma unroll
        for (int ksb = 0; ksb < KB; ++ksb) {
          const int ks = half * KB + ksb;
          const int k  = kh * (KSL * 32) + ks * 32 + lk8;
          #pragma unroll
          for (int mt = 0; mt < 2; ++mt) {
            const int m = mh * 32 + mt * 16 + l15;
            if (LAYER == 0) {
              if (k < II) af[ksb][mt] = *(const bf16x8*)(P.xb + ((size_t)t * BB + m) * II + k);
              else        af[ksb][mt] = ld_bypass(h0prev + (size_t)m * HH + (k - II));
            } else {
              if (k < HH) af[ksb][mt] = ld_bypass(h0cur + (size_t)m * HH + k);
              else        af[ksb][mt] = ld_bypass(h1prev + (size_t)m * HH + (k - HH));
            }
          }
        }
        asm volatile("s_waitcnt vmcnt(0)" ::: "memory");
        __builtin_amdgcn_sched_barrier(0);
        #pragma unroll
        for (int ksb = 0; ksb < KB; ++ksb) {
          const int ks = half * KB + ksb;
          #pragma unroll
          for (int mt = 0; mt < 2; ++mt)
            #pragma unroll
            for (int nt = 0; nt < 4; ++nt)
              acc[mt][nt] = __builtin_amdgcn_mfma_f32_16x16x32_bf16(af[ksb][mt], wf[nt][ks], acc[mt][nt], 0, 0, 0);
        }
      }

      // stage A: waves 4..7 write partials
      if (kh >= 4) {
        #pragma unroll
        for (int mt = 0; mt < 2; ++mt)
          #pragma unroll
          for (int nt = 0; nt < 4; ++nt) {
            int col = nt * 16 + l15;
            int mb  = mt * 16 + (lane >> 4) * 4;
            *(f32x4*)&pbuf[kh - 4][col][mb] = acc[mt][nt];
          }
      }
    }
    __syncthreads();
    if (active && kh < 4) {
      #pragma unroll
      for (int mt = 0; mt < 2; ++mt)
        #pragma unroll
        for (int nt = 0; nt < 4; ++nt) {
          int col = nt * 16 + l15;
          int mb  = mt * 16 + (lane >> 4) * 4;
          f32x4 v = *(const f32x4*)&pbuf[kh][col][mb];
          acc[mt][nt] += v;
          *(f32x4*)&pbuf[kh][col][mb] = acc[mt][nt];
        }
    }
    __syncthreads();
    // cell update: 128 threads, each owns (m-quad q, unit j)
    if (active && tid < 128) {
      int q = tid >> 4, j = tid & 15;
      f32x4 gv[4];
      #pragma unroll
      for (int g = 0; g < 4; ++g) {
        int col = g * 16 + j;
        f32x4 s = *(const f32x4*)&pbuf[0][col][q * 4];
        #pragma unroll
        for (int w = 1; w < 4; ++w) s += *(const f32x4*)&pbuf[w][col][q * 4];
        gv[g] = s;
      }
      #pragma unroll
      for (int r = 0; r < 4; ++r) {
        int m = q * 4 + r;
        float iv = 1.f / (1.f + __expf(-(gv[0][r] + bv[0])));
        float fv = 1.f / (1.f + __expf(-(gv[1][r] + bv[1])));
        float gg = tanhf(gv[2][r] + bv[2]);
        float ov = 1.f / (1.f + __expf(-(gv[3][r] + bv[3])));
        float c = fv * cb[m][j] + iv * gg;
        cb[m][j] = c;
        float h = ov * tanhf(c);
        int mg = mh * 32 + m;
        int unit = ns * 16 + j;
        unsigned int hb = f2bf(h);
        if (LAYER == 0) {
          st_bypass_u16(P.h0 + (size_t)(t & 1) * BH + (size_t)mg * HH + unit, hb);
          if (t == TT - 1) P.out[TBH + (size_t)mg * HH + unit] = h;
        } else {
          st_bypass_u16(P.h1 + (size_t)(t & 1) * BH + (size_t)mg * HH + unit, hb);
          P.out[(size_t)t * BH + (size_t)mg * HH + unit] = h;
          if (t == TT - 1) P.out[TBH + BH + (size_t)mg * HH + unit] = h;
        }
      }
    }
    gridbar(P.ctr, (unsigned)(NBLK / NCTR) * (unsigned)(p + 1), tid);
  }

  // final cell state c_f
  if (tid < 128) {
    int q = tid >> 4, j = tid & 15;
    #pragma unroll
    for (int r = 0; r < 4; ++r) {
      int m = q * 4 + r;
      int mg = mh * 32 + m;
      int unit = ns * 16 + j;
      P.out[TBH + (size_t)(2 + LAYER) * BH + (size_t)mg * HH + unit] = cb[m][j];
    }
  }
}

__global__ void __launch_bounds__(NTHR, 2) lstm_kernel(Params P) {
  __shared__ float pbuf[4][64][36];
  __shared__ float cb[32][16];
  if (blockIdx.x < 128) body<0>(P, pbuf, cb);
  else                  body<1>(P, pbuf, cb);
}

extern "C" void kernel_launch(void* const* d_in, const int* in_sizes, int n_in,
                              void* d_out, int out_size, void* d_ws, size_t ws_size,
                              hipStream_t stream) {
  const float* x = (const float*)d_in[0];
  Params P;
  P.wih0 = (const float*)d_in[1];
  P.whh0 = (const float*)d_in[2];
  P.bih0 = (const float*)d_in[3];
  P.bhh0 = (const float*)d_in[4];
  P.wih1 = (const float*)d_in[5];
  P.whh1 = (const float*)d_in[6];
  P.bih1 = (const float*)d_in[7];
  P.bhh1 = (const float*)d_in[8];
  P.out  = (float*)d_out;

  char* ws = (char*)d_ws;
  P.ctr = (unsigned int*)ws;                               // 32 ctrs * 128B = 4KB (pad to 8KB)
  P.xb  = (const unsigned short*)(ws + 8192);
  unsigned short* xb_w = (unsigned short*)(ws + 8192);
  P.h0  = (unsigned short*)(ws + 8192 + (size_t)TT * BB * II * 2);
  P.h1  = P.h0 + (size_t)2 * BB * HH;

  hipMemsetAsync((void*)P.ctr, 0, 8192, stream);
  hipMemsetAsync((void*)P.h0, 0, (size_t)4 * BB * HH * sizeof(unsigned short), stream);

  int n8 = TT * BB * II / 8;
  cvt_kernel<<<2048, 256, 0, stream>>>(x, xb_w, n8);

  void* args[] = { &P };
  hipLaunchCooperativeKernel((void*)lstm_kernel, dim3(NBLK), dim3(NTHR), args, 0, stream);
}